// Round 1
// 3997.456 us; speedup vs baseline: 1.1124x; 1.1124x over previous
//
#include <hip/hip_runtime.h>
#include <cstdint>
#include <cstddef>

typedef unsigned int u32;
typedef unsigned long long u64;
typedef __uint128_t u128;

#define TT 1024
#define BB 32
#define DDIM 1024
#define RRANK 64
#define BD (BB*DDIM)        /* 32768 */
#define TBD (TT*BB*DDIM)    /* 33554432 */

// ---------------- constexpr double math (compile-time ziggurat tables) ----------------
constexpr double kLN2 = 0.6931471805599453094172321214581766;

constexpr double cexp_(double x){
  int k = (int)(x / kLN2 + (x >= 0.0 ? 0.5 : -0.5));
  double r = x - (double)k * kLN2;
  double term = 1.0, sum = 1.0;
  for (int n = 1; n <= 26; ++n){ term *= r / (double)n; sum += term; }
  double p = 1.0; int kk = k;
  while (kk > 0){ p *= 2.0; --kk; }
  while (kk < 0){ p *= 0.5; ++kk; }
  return sum * p;
}
constexpr double clog_(double x){
  int e = 0; double m = x;
  while (m >= 1.3348398541700344) { m *= 0.5; ++e; }
  while (m <  0.6674199270850172) { m *= 2.0; --e; }
  double s = (m - 1.0) / (m + 1.0);
  double s2 = s * s, term = s, sum = 0.0;
  for (int n = 0; n < 20; ++n){ sum += term / (double)(2*n+1); term *= s2; }
  return 2.0 * sum + (double)e * kLN2;
}
constexpr double csqrt_(double x){
  double g = 0.5 * (x + 1.0);
  for (int i = 0; i < 40; ++i) g = 0.5 * (g + x / g);
  return g;
}

constexpr double ZIG_R    = 3.6541528853610087963519472518;
constexpr double ZIG_INVR = 0.27366123732975827203338247596;
constexpr double ZIG_V    = 4.92867323399e-3;   // area/strip, n=256 normal ziggurat

struct ZigT { u64 ki[256]; double wi[256]; double fi[256]; };

constexpr ZigT make_zig(){
  ZigT t{};
  const double m1 = 4503599627370496.0;  // 2^52
  double dn = ZIG_R, tn = ZIG_R;
  const double vn = ZIG_V;
  const double q = vn / cexp_(-0.5 * dn * dn);
  t.ki[0] = (u64)((dn / q) * m1);
  t.ki[1] = 0;
  t.wi[0] = q / m1;
  t.wi[255] = dn / m1;
  t.fi[0] = 1.0;
  t.fi[255] = cexp_(-0.5 * dn * dn);
  for (int i = 254; i >= 1; --i){
    dn = csqrt_(-2.0 * clog_(vn / dn + cexp_(-0.5 * dn * dn)));
    t.ki[i+1] = (u64)((dn / tn) * m1);
    tn = dn;
    t.fi[i] = cexp_(-0.5 * dn * dn);
    t.wi[i] = dn / m1;
  }
  return t;
}

__device__ const ZigT ZT = make_zig();

// ---------------- helpers ----------------
__device__ __forceinline__ float block_sum_1024(float v, float* buf, int tid){
  buf[tid] = v; __syncthreads();
  #pragma unroll 1
  for (int s = 512; s > 0; s >>= 1){
    if (tid < s) buf[tid] += buf[tid + s];
    __syncthreads();
  }
  float r = buf[0];
  __syncthreads();
  return r;
}

// ---------------- K1: exact numpy RNG + power iteration -> scale ----------------
__global__ __launch_bounds__(1024) void k1_spectral(const float* __restrict__ U,
    const float* __restrict__ V, float* __restrict__ wsp){
  __shared__ float u_sh[1024];
  __shared__ float v_sh[1024];
  __shared__ float part[1024];
  __shared__ float t_sh[64];
  __shared__ float s_sh[64];
  __shared__ u64 ki_s[256];
  __shared__ double wi_s[256];
  __shared__ double fi_s[256];
  const int tid = threadIdx.x;
  if (tid < 256){ ki_s[tid] = ZT.ki[tid]; wi_s[tid] = ZT.wi[tid]; fi_s[tid] = ZT.fi[tid]; }
  __syncthreads();

  if (tid == 0){
    // ---- SeedSequence(0): pool mixing (O'Neill seed_seq_fe constants) ----
    u32 hc = 0x43b0d7e5u;
    u32 pool[4];
    for (int i = 0; i < 4; ++i){
      u32 v = 0u;                       // entropy = [0]; i>=1 hashes 0 too
      v ^= hc; hc *= 0x931e8875u; v *= hc; v ^= v >> 16;
      pool[i] = v;
    }
    for (int s = 0; s < 4; ++s){
      for (int d = 0; d < 4; ++d){
        if (s == d) continue;
        u32 v = pool[s];
        v ^= hc; hc *= 0x931e8875u; v *= hc; v ^= v >> 16;
        u32 r = 0xca01f9ddu * pool[d] - 0x4973f715u * v;
        r ^= r >> 16;
        pool[d] = r;
      }
    }
    // generate_state(4, uint64) -> 8 x uint32, little-endian pairs
    u32 ghc = 0x8b51f9ddu;
    u32 st32[8];
    for (int i = 0; i < 8; ++i){
      u32 dv = pool[i & 3];
      dv ^= ghc; ghc *= 0x58f38dedu; dv *= ghc; dv ^= dv >> 16;
      st32[i] = dv;
    }
    u64 sd0 = (u64)st32[0] | ((u64)st32[1] << 32);
    u64 sd1 = (u64)st32[2] | ((u64)st32[3] << 32);
    u64 sd2 = (u64)st32[4] | ((u64)st32[5] << 32);
    u64 sd3 = (u64)st32[6] | ((u64)st32[7] << 32);
    // ---- PCG64 (setseq_128, XSL-RR), numpy default ----
    const u128 MULT = ((u128)2549297995355413924ULL << 64) | (u128)4865540595714422341ULL;
    u128 initstate = ((u128)sd0 << 64) | (u128)sd1;  // seed[0] = high
    u128 initseq   = ((u128)sd2 << 64) | (u128)sd3;
    u128 state = 0;
    u128 inc = (initseq << 1) | (u128)1;
    state = state * MULT + inc;
    state += initstate;
    state = state * MULT + inc;
    // ---- ziggurat standard_normal, numpy layout, sequential fill ----
    int filled = 0;
    while (filled < 1024){
      state = state * MULT + inc;
      u64 hi = (u64)(state >> 64), lo = (u64)state;
      u32 rot = (u32)(state >> 122);
      u64 ru = hi ^ lo;
      ru = (ru >> rot) | (ru << ((64u - rot) & 63u));
      int idx = (int)(ru & 0xff);
      u64 r9 = ru >> 8;
      int sgn = (int)(r9 & 1);
      u64 rabs = (r9 >> 1) & 0x000fffffffffffffULL;
      double x = (double)rabs * wi_s[idx];
      if (sgn) x = -x;
      if (rabs < ki_s[idx]){ u_sh[filled++] = (float)x; continue; }
      if (idx == 0){
        for (;;){
          state = state * MULT + inc;
          u64 h1 = (u64)(state>>64), l1 = (u64)state; u32 ro1 = (u32)(state>>122);
          u64 a = h1 ^ l1; a = (a>>ro1)|(a<<((64u-ro1)&63u));
          double ua = (double)(a >> 11) * (1.0/9007199254740992.0);
          state = state * MULT + inc;
          u64 h2 = (u64)(state>>64), l2 = (u64)state; u32 ro2 = (u32)(state>>122);
          u64 bd = h2 ^ l2; bd = (bd>>ro2)|(bd<<((64u-ro2)&63u));
          double ub = (double)(bd >> 11) * (1.0/9007199254740992.0);
          double xt = -ZIG_INVR * log1p(-ua);
          double yt = -log1p(-ub);
          if (yt + yt > xt * xt){
            double val = ((rabs >> 8) & 1) ? -(ZIG_R + xt) : (ZIG_R + xt);
            u_sh[filled++] = (float)val;
            break;
          }
        }
        continue;
      }
      state = state * MULT + inc;
      u64 h3 = (u64)(state>>64), l3 = (u64)state; u32 ro3 = (u32)(state>>122);
      u64 c = h3 ^ l3; c = (c>>ro3)|(c<<((64u-ro3)&63u));
      double uc = (double)(c >> 11) * (1.0/9007199254740992.0);
      if ((fi_s[idx-1] - fi_s[idx]) * uc + fi_s[idx] < exp(-0.5 * x * x)){
        u_sh[filled++] = (float)x;
      }
      // else: retry with a fresh draw
    }
  }
  __syncthreads();

  // ---- normalize u0 (no eps, matches reference) ----
  float uv = u_sh[tid];
  float ss = block_sum_1024(uv * uv, part, tid);
  float nrm = sqrtf(ss);
  u_sh[tid] = uv / nrm;
  __syncthreads();

  // ---- 3 power iterations on A = U V via factors ----
  for (int it = 0; it < 3; ++it){
    { // t = U^T u   (U is [D][R], lanes over r -> coalesced)
      const int r = tid & 63, g = tid >> 6;
      float p = 0.f;
      for (int j = 0; j < 64; ++j) p += U[(size_t)(g*64+j)*64 + r] * u_sh[g*64+j];
      part[tid] = p;
    }
    __syncthreads();
    if (tid < 64){ float s = 0.f; for (int g = 0; g < 16; ++g) s += part[g*64+tid]; t_sh[tid] = s; }
    __syncthreads();
    // v = V^T t ; normalize with +eps
    float vvv = 0.f;
    for (int r = 0; r < 64; ++r) vvv += V[(size_t)r*1024 + tid] * t_sh[r];
    float nv = sqrtf(block_sum_1024(vvv*vvv, part, tid)) + 1e-8f;
    vvv /= nv;
    v_sh[tid] = vvv;
    __syncthreads();
    { // s = V v
      const int r = tid & 63, g = tid >> 6;
      float p = 0.f;
      for (int j = 0; j < 64; ++j) p += V[(size_t)r*1024 + g*64 + j] * v_sh[g*64+j];
      part[tid] = p;
    }
    __syncthreads();
    if (tid < 64){ float s = 0.f; for (int g = 0; g < 16; ++g) s += part[g*64+tid]; s_sh[tid] = s; }
    __syncthreads();
    // u = U s ; normalize with +eps
    float uuu = 0.f;
    for (int r = 0; r < 64; ++r) uuu += U[(size_t)tid*64 + r] * s_sh[r];
    float nu = sqrtf(block_sum_1024(uuu*uuu, part, tid)) + 1e-8f;
    uuu /= nu;
    u_sh[tid] = uuu;
    __syncthreads();
  }
  // sigma = |(U^T u) . (V v)| ; s_sh still holds V v from last iteration
  {
    const int r = tid & 63, g = tid >> 6;
    float p = 0.f;
    for (int j = 0; j < 64; ++j) p += U[(size_t)(g*64+j)*64 + r] * u_sh[g*64+j];
    part[tid] = p;
  }
  __syncthreads();
  if (tid < 64){ float s = 0.f; for (int g = 0; g < 16; ++g) s += part[g*64+tid]; t_sh[tid] = s; }
  __syncthreads();
  if (tid == 0){
    float sig = 0.f;
    for (int r = 0; r < 64; ++r) sig += t_sh[r] * s_sh[r];
    sig = fabsf(sig);
    wsp[0] = 0.95f / (sig + 1e-8f);   // = s^2, folded once into tmp per step
  }
}

// ---------------- K2: xW = x @ W^T + b  (fp32, NT, writes into h_all slots 1..T) ----------------
__global__ __launch_bounds__(256) void k2_gemm(const float* __restrict__ X,
    const float* __restrict__ W, const float* __restrict__ bvec,
    float* __restrict__ C){
  __shared__ float As[16][132];   // [k][m], padded: 132%4==0 keeps b128 alignment
  __shared__ float Ws[16][68];    // [k][n]
  const int bm = blockIdx.y * 128;
  const int bn = blockIdx.x * 64;
  const int tid = (int)threadIdx.x;
  const int tx = tid & 15;        // n-dir
  const int ty = tid >> 4;        // m-dir
  const int lm = tid >> 2;        // 0..63
  const int lk = (tid & 3) * 4;   // 0,4,8,12
  float acc[8][4];
  #pragma unroll
  for (int i = 0; i < 8; ++i)
    #pragma unroll
    for (int j = 0; j < 4; ++j) acc[i][j] = 0.f;

  #pragma unroll 1
  for (int k0 = 0; k0 < 1024; k0 += 16){
    float4 a0 = *(const float4*)(X + (size_t)(bm+lm)*1024 + k0 + lk);
    float4 a1 = *(const float4*)(X + (size_t)(bm+64+lm)*1024 + k0 + lk);
    float4 w0 = *(const float4*)(W + (size_t)(bn+lm)*1024 + k0 + lk);
    As[lk+0][lm] = a0.x; As[lk+1][lm] = a0.y; As[lk+2][lm] = a0.z; As[lk+3][lm] = a0.w;
    As[lk+0][64+lm] = a1.x; As[lk+1][64+lm] = a1.y; As[lk+2][64+lm] = a1.z; As[lk+3][64+lm] = a1.w;
    Ws[lk+0][lm] = w0.x; Ws[lk+1][lm] = w0.y; Ws[lk+2][lm] = w0.z; Ws[lk+3][lm] = w0.w;
    __syncthreads();
    #pragma unroll
    for (int k = 0; k < 16; ++k){
      float4 av0 = *(const float4*)&As[k][ty*8];
      float4 av1 = *(const float4*)&As[k][ty*8+4];
      float4 wv  = *(const float4*)&Ws[k][tx*4];
      const float am[8] = {av0.x,av0.y,av0.z,av0.w,av1.x,av1.y,av1.z,av1.w};
      const float wn[4] = {wv.x,wv.y,wv.z,wv.w};
      #pragma unroll
      for (int i = 0; i < 8; ++i)
        #pragma unroll
        for (int j = 0; j < 4; ++j) acc[i][j] += am[i]*wn[j];
    }
    __syncthreads();
  }
  const float4 bv = *(const float4*)(bvec + bn + tx*4);
  #pragma unroll
  for (int i = 0; i < 8; ++i){
    const int row = bm + ty*8 + i;
    float4 o;
    o.x = acc[i][0] + bv.x;
    o.y = acc[i][1] + bv.y;
    o.z = acc[i][2] + bv.z;
    o.w = acc[i][3] + bv.w;
    *(float4*)(C + (size_t)row*1024 + bn + tx*4) = o;
  }
}

// ---------------- K3: sequential recurrence, one workgroup per batch ----------------
// v2: fit the 128-reg/wave cap (16 waves resident):
//   ureg[64] (U row) + vregA[32] (V row, j=0..31) in registers (~118 regs total, no spill);
//   V row j=32..63 staged once in LDS (128 KB, 16B-granule XOR swizzle -> 2-way = free).
// h and tmp broadcasts via *uniform* ds_read_b128 (replaces 128 v_readlane/step).
// xW prefetched one full step ahead. Accumulation order bit-identical to v1.
__global__ __launch_bounds__(1024) void k3_recur(const float* __restrict__ U,
    const float* __restrict__ V, const float* __restrict__ h0,
    const float* __restrict__ wsp, float* __restrict__ hall){
  __shared__ float h_sh[1024];
  __shared__ float part[1024];
  __shared__ __align__(16) float tmp_sh[64];
  __shared__ __align__(16) float VB[32768];   // 128KB: [r][wv][granule^(r&7)][4]
  const int tid = (int)threadIdx.x;
  const int lane = tid & 63;
  const int wv = tid >> 6;
  const int b = (int)blockIdx.x;
  const float scale = wsp[0];

  // ---- stage VB: V[r][c*64+32+j], j=0..31, granule-swizzled ----
  {
    const int r = tid >> 4, c = tid & 15;
    const float* src = V + (size_t)r*1024 + c*64 + 32;
    float* dst = VB + r*512 + c*32;
    #pragma unroll
    for (int g = 0; g < 8; ++g){
      float4 v4 = *(const float4*)(src + g*4);
      *(float4*)(dst + (((g ^ (r & 7))) << 2)) = v4;
    }
  }
  // ---- vregA: V[lane][wv*64 + 0..31] ----
  float vregA[32];
  #pragma unroll
  for (int q = 0; q < 8; ++q){
    float4 t4 = *(const float4*)(V + (size_t)lane*1024 + wv*64 + q*4);
    vregA[q*4+0]=t4.x; vregA[q*4+1]=t4.y; vregA[q*4+2]=t4.z; vregA[q*4+3]=t4.w;
  }
  // ---- ureg: U[tid][0..63] ----
  float ureg[64];
  #pragma unroll
  for (int q = 0; q < 16; ++q){
    float4 t4 = *(const float4*)(U + (size_t)tid*64 + q*4);
    ureg[q*4+0]=t4.x; ureg[q*4+1]=t4.y; ureg[q*4+2]=t4.z; ureg[q*4+3]=t4.w;
  }
  // per-lane VB read base (granule offsets folded per q at compile time via XOR below)
  const float* vb_lane = VB + lane*512 + wv*32;
  const int r7 = lane & 7;

  float h = h0[b*1024 + tid];
  h_sh[tid] = h;
  float* base = hall + BD + (size_t)b*1024 + tid;
  float xwv = base[0];                 // xW(0) preloaded
  __syncthreads();                     // VB staged (cross-wave) + h_sh ready

  #pragma unroll 1
  for (int t = 0; t < TT; ++t){
    const int tn = (t < TT-1) ? t+1 : t;
    const float xw_next = base[(size_t)tn*BD];   // prefetch next step's xW

    // ph1: partial tmp[lane] over d-chunk [wv*64, wv*64+64)
    // (p: even j ascending, p2: odd j ascending -- identical to v1 chains)
    float p = 0.f, p2 = 0.f;
    #pragma unroll
    for (int q = 0; q < 8; ++q){
      float4 h4 = *(const float4*)(h_sh + wv*64 + q*4);     // uniform broadcast
      p  = fmaf(h4.x, vregA[q*4+0], p);
      p2 = fmaf(h4.y, vregA[q*4+1], p2);
      p  = fmaf(h4.z, vregA[q*4+2], p);
      p2 = fmaf(h4.w, vregA[q*4+3], p2);
    }
    #pragma unroll
    for (int q = 0; q < 8; ++q){
      float4 h4 = *(const float4*)(h_sh + wv*64 + 32 + q*4);        // uniform
      float4 v4 = *(const float4*)(vb_lane + ((q ^ r7) << 2));      // swizzled, 2-way
      p  = fmaf(h4.x, v4.x, p);
      p2 = fmaf(h4.y, v4.y, p2);
      p  = fmaf(h4.z, v4.z, p);
      p2 = fmaf(h4.w, v4.w, p2);
    }
    part[tid] = p + p2;
    __syncthreads();
    if (tid < 64){
      float s = 0.f;
      #pragma unroll
      for (int g = 0; g < 16; ++g) s += part[g*64 + tid];
      tmp_sh[tid] = s * scale;
    }
    __syncthreads();
    // ph2: a = sum_r tmp[r]*U[tid][r]  (a0: even r, a1: odd r, ascending)
    float a0 = 0.f, a1 = 0.f;
    #pragma unroll
    for (int q = 0; q < 16; ++q){
      float4 t4 = *(const float4*)(tmp_sh + q*4);           // uniform broadcast
      a0 = fmaf(t4.x, ureg[q*4+0], a0);
      a1 = fmaf(t4.y, ureg[q*4+1], a1);
      a0 = fmaf(t4.z, ureg[q*4+2], a0);
      a1 = fmaf(t4.w, ureg[q*4+3], a1);
    }
    h = tanhf(xwv + a0 + a1);
    base[(size_t)t*BD] = h;            // overwrite xW slot with h_{t+1}
    h_sh[tid] = h;                     // own-wave chunk only -> no barrier needed
    xwv = xw_next;
  }
}

// ---------------- K4: outs = h_{t+1} * silu(z); h_all[0] = h0 ----------------
__global__ __launch_bounds__(256) void k4_out(const float* __restrict__ z,
    const float* __restrict__ h0, float* __restrict__ dout){
  const int i = (int)(blockIdx.x * blockDim.x + threadIdx.x);  // float4 index < 8388608
  const float4 zv = *((const float4*)z + i);
  const float4 hv = *((const float4*)(dout + TBD + BD) + i);
  float4 o;
  o.x = hv.x * (zv.x / (1.f + expf(-zv.x)));
  o.y = hv.y * (zv.y / (1.f + expf(-zv.y)));
  o.z = hv.z * (zv.z / (1.f + expf(-zv.z)));
  o.w = hv.w * (zv.w / (1.f + expf(-zv.w)));
  *((float4*)dout + i) = o;
  if (i < BD/4){
    *((float4*)(dout + TBD) + i) = *((const float4*)h0 + i);
  }
}

// ---------------- launch ----------------
extern "C" void kernel_launch(void* const* d_in, const int* in_sizes, int n_in,
                              void* d_out, int out_size, void* d_ws, size_t ws_size,
                              hipStream_t stream) {
  (void)in_sizes; (void)n_in; (void)out_size; (void)ws_size;
  const float* x    = (const float*)d_in[0];
  const float* z    = (const float*)d_in[1];
  const float* h0   = (const float*)d_in[2];
  const float* Wx   = (const float*)d_in[3];
  const float* U    = (const float*)d_in[4];
  const float* V    = (const float*)d_in[5];
  const float* bias = (const float*)d_in[6];
  float* outp = (float*)d_out;
  float* hall = outp + (size_t)TBD;
  float* wsp  = (float*)d_ws;

  k1_spectral<<<1, 1024, 0, stream>>>(U, V, wsp);
  dim3 g2(1024/64, 32768/128);   // (n-tiles=16, m-tiles=256)
  k2_gemm<<<g2, 256, 0, stream>>>(x, Wx, bias, hall + BD);
  k3_recur<<<BB, 1024, 0, stream>>>(U, V, h0, wsp, hall);
  k4_out<<<TBD/4/256, 256, 0, stream>>>(z, h0, outp);
}